// Round 2
// baseline (1703.446 us; speedup 1.0000x reference)
//
#include <hip/hip_runtime.h>

typedef float  f32x2  __attribute__((ext_vector_type(2)));
typedef float  f32x4  __attribute__((ext_vector_type(4)));
typedef __bf16 bf16x8 __attribute__((ext_vector_type(8)));

// split fp32 pair into packed bf16 hi-pair and lo-pair (3-term MFMA emulation)
static __device__ __forceinline__ void split_pair(float a, float b, unsigned& hp, unsigned& lp) {
    __bf16 ha = (__bf16)a, hb = (__bf16)b;
    hp = (unsigned)__builtin_bit_cast(unsigned short, ha) |
         ((unsigned)__builtin_bit_cast(unsigned short, hb) << 16);
    __bf16 la = (__bf16)(a - (float)ha), lb = (__bf16)(b - (float)hb);
    lp = (unsigned)__builtin_bit_cast(unsigned short, la) |
         ((unsigned)__builtin_bit_cast(unsigned short, lb) << 16);
}

// ============ CSR bucket build (order-free; buckets padded to multiple of 8) ============
__global__ __launch_bounds__(256) void hist_rows(const int* __restrict__ row, int* __restrict__ cnt, int E) {
    int e = blockIdx.x * 256 + threadIdx.x;
    if (e < E) atomicAdd(&cnt[row[e]], 1);
}

__global__ __launch_bounds__(256) void alloc_buckets(const int* __restrict__ cnt,
                                                     int* __restrict__ base, int* __restrict__ fill,
                                                     float* __restrict__ dinv,
                                                     int* __restrict__ total,
                                                     int2* __restrict__ edge2, int n) {
    int i = blockIdx.x * 256 + threadIdx.x;
    if (i >= n) return;
    int c = cnt[i];
    int cp = (c + 7) & ~7;                 // pad to x8
    int b = atomicAdd(total, cp);
    base[i] = b;
    fill[i] = b;
    dinv[i] = rsqrtf(1.0f + (float)c);     // +1 self-loop
    for (int p = b + c; p < b + cp; ++p) edge2[p] = make_int2(0, 0);  // pad: gathers idx0 * 0.0
}

__global__ __launch_bounds__(256) void fill_buckets(const int* __restrict__ row, const int* __restrict__ col,
                                                    int* __restrict__ fill, const float* __restrict__ dinv,
                                                    int2* __restrict__ edge2, int E) {
    int e = blockIdx.x * 256 + threadIdx.x;
    if (e < E) {
        int r = row[e], c = col[e];
        int pos = atomicAdd(&fill[r], 1);
        edge2[pos] = make_int2(c, __float_as_int(dinv[r] * dinv[c]));
    }
}

// ============ aggregate x (128 feats, float2/lane), software-pipelined; rep = attribution loop ============
__global__ __launch_bounds__(256) void agg_x(const float* __restrict__ x,
                                             const int* __restrict__ base, const int* __restrict__ cnt,
                                             const int2* __restrict__ edge2, const float* __restrict__ dinv,
                                             float* __restrict__ AGGX, int n, int rep) {
    int w = (blockIdx.x * 256 + threadIdx.x) >> 6;
    int lane = threadIdx.x & 63;
    if (w >= n) return;
    for (int it = 0; it < rep; ++it) {
        asm volatile("" ::: "memory");     // defeat cross-rep hoisting/CSE
        float di = dinv[w];
        f32x2 xv = ((const f32x2*)(x + (size_t)w * 128))[lane];
        f32x2 a0 = xv * (di * di);
        f32x2 a1 = {0.f, 0.f}, a2 = {0.f, 0.f}, a3 = {0.f, 0.f};
        const int2* eb = edge2 + base[w];
        int dp = (cnt[w] + 7) & ~7;
        if (dp > 0) {
            int2 e[8];
            #pragma unroll
            for (int u = 0; u < 8; ++u) e[u] = eb[u];
            int j = 0;
            for (; j + 8 < dp; j += 8) {
                f32x2 v[8];
                #pragma unroll
                for (int u = 0; u < 8; ++u)
                    v[u] = ((const f32x2*)(x + (size_t)e[u].x * 128))[lane];
                int2 en[8];
                #pragma unroll
                for (int u = 0; u < 8; ++u) en[u] = eb[j + 8 + u];
                #pragma unroll
                for (int u = 0; u < 8; ++u) {
                    float nr = __int_as_float(e[u].y);
                    f32x2* a = (u & 3) == 0 ? &a0 : (u & 3) == 1 ? &a1 : (u & 3) == 2 ? &a2 : &a3;
                    *a += v[u] * nr;
                }
                #pragma unroll
                for (int u = 0; u < 8; ++u) e[u] = en[u];
            }
            {
                f32x2 v[8];
                #pragma unroll
                for (int u = 0; u < 8; ++u)
                    v[u] = ((const f32x2*)(x + (size_t)e[u].x * 128))[lane];
                #pragma unroll
                for (int u = 0; u < 8; ++u) {
                    float nr = __int_as_float(e[u].y);
                    f32x2* a = (u & 3) == 0 ? &a0 : (u & 3) == 1 ? &a1 : (u & 3) == 2 ? &a2 : &a3;
                    *a += v[u] * nr;
                }
            }
        }
        f32x2 o = a0 + a1 + a2 + a3;
        __builtin_nontemporal_store(o, (f32x2*)(AGGX + (size_t)w * 128) + lane);
    }
}

// ============ fused: aggregate H2 (64 feats) + bias + log_softmax + 24-copy broadcast ============
// Requires H2/edge2/meta to live OUTSIDE d_out (d_ws), since this kernel overwrites all of d_out.
__global__ __launch_bounds__(256) void agg_h2_final(const float* __restrict__ H2,
                                                    const int* __restrict__ base, const int* __restrict__ cnt,
                                                    const int2* __restrict__ edge2, const float* __restrict__ dinv,
                                                    const float* __restrict__ b2,
                                                    float* __restrict__ out, int n, int copies, int rep) {
    int w = (blockIdx.x * 256 + threadIdx.x) >> 6;
    int lane = threadIdx.x & 63;
    if (w >= n) return;
    for (int it = 0; it < rep; ++it) {
        asm volatile("" ::: "memory");
        float di = dinv[w];
        float a0 = H2[(size_t)w * 64 + lane] * di * di;
        float a1 = 0.f, a2 = 0.f, a3 = 0.f;
        const int2* eb = edge2 + base[w];
        int dp = (cnt[w] + 7) & ~7;
        if (dp > 0) {
            int2 e[8];
            #pragma unroll
            for (int u = 0; u < 8; ++u) e[u] = eb[u];
            int j = 0;
            for (; j + 8 < dp; j += 8) {
                float v[8];
                #pragma unroll
                for (int u = 0; u < 8; ++u)
                    v[u] = H2[(size_t)e[u].x * 64 + lane];
                int2 en[8];
                #pragma unroll
                for (int u = 0; u < 8; ++u) en[u] = eb[j + 8 + u];
                #pragma unroll
                for (int u = 0; u < 8; ++u) {
                    float nr = __int_as_float(e[u].y);
                    float* a = (u & 3) == 0 ? &a0 : (u & 3) == 1 ? &a1 : (u & 3) == 2 ? &a2 : &a3;
                    *a = fmaf(v[u], nr, *a);
                }
                #pragma unroll
                for (int u = 0; u < 8; ++u) e[u] = en[u];
            }
            {
                float v[8];
                #pragma unroll
                for (int u = 0; u < 8; ++u)
                    v[u] = H2[(size_t)e[u].x * 64 + lane];
                #pragma unroll
                for (int u = 0; u < 8; ++u) {
                    float nr = __int_as_float(e[u].y);
                    float* a = (u & 3) == 0 ? &a0 : (u & 3) == 1 ? &a1 : (u & 3) == 2 ? &a2 : &a3;
                    *a = fmaf(v[u], nr, *a);
                }
            }
        }
        float v = a0 + a1 + a2 + a3 + b2[lane];
        float m = v;
        #pragma unroll
        for (int off = 32; off > 0; off >>= 1) m = fmaxf(m, __shfl_xor(m, off, 64));
        float e = expf(v - m);
        float s = e;
        #pragma unroll
        for (int off = 32; off > 0; off >>= 1) s += __shfl_xor(s, off, 64);
        float res = v - m - logf(s);
        size_t idx = (size_t)w * 64 + lane;
        size_t stride = (size_t)n * 64;
        for (int c = 0; c < copies; ++c)
            __builtin_nontemporal_store(res, out + (size_t)c * stride + idx);
    }
}

// ============ fallback unfused pair (round-1 semantics, d_out-as-workspace layout) ============
__global__ __launch_bounds__(256) void agg_h2(const float* __restrict__ H2,
                                              const int* __restrict__ base, const int* __restrict__ cnt,
                                              const int2* __restrict__ edge2, const float* __restrict__ dinv,
                                              const float* __restrict__ b2,
                                              float* __restrict__ AGG2, int n, int rep) {
    int w = (blockIdx.x * 256 + threadIdx.x) >> 6;
    int lane = threadIdx.x & 63;
    if (w >= n) return;
    for (int it = 0; it < rep; ++it) {
        asm volatile("" ::: "memory");
        float di = dinv[w];
        float a0 = H2[(size_t)w * 64 + lane] * di * di;
        float a1 = 0.f, a2 = 0.f, a3 = 0.f;
        const int2* eb = edge2 + base[w];
        int dp = (cnt[w] + 7) & ~7;
        for (int j = 0; j < dp; j += 8) {
            int2 e[8];
            #pragma unroll
            for (int u = 0; u < 8; ++u) e[u] = eb[j + u];
            float v[8];
            #pragma unroll
            for (int u = 0; u < 8; ++u) v[u] = H2[(size_t)e[u].x * 64 + lane];
            #pragma unroll
            for (int u = 0; u < 8; ++u) {
                float nr = __int_as_float(e[u].y);
                float* a = (u & 3) == 0 ? &a0 : (u & 3) == 1 ? &a1 : (u & 3) == 2 ? &a2 : &a3;
                *a = fmaf(v[u], nr, *a);
            }
        }
        __builtin_nontemporal_store(a0 + a1 + a2 + a3 + b2[lane], AGG2 + (size_t)w * 64 + lane);
    }
}

__global__ __launch_bounds__(256) void final_out(const float* __restrict__ AGG2,
                                                 float* __restrict__ out, int n, int copies, int rep) {
    int w = (blockIdx.x * 256 + threadIdx.x) >> 6;
    int lane = threadIdx.x & 63;
    if (w >= n) return;
    for (int it = 0; it < rep; ++it) {
        asm volatile("" ::: "memory");
        size_t idx = (size_t)w * 64 + lane;
        float v = __builtin_nontemporal_load(AGG2 + idx);
        float m = v;
        #pragma unroll
        for (int off = 32; off > 0; off >>= 1) m = fmaxf(m, __shfl_xor(m, off, 64));
        float e = expf(v - m);
        float s = e;
        #pragma unroll
        for (int off = 32; off > 0; off >>= 1) s += __shfl_xor(s, off, 64);
        float res = v - m - logf(s);
        size_t stride = (size_t)n * 64;
        for (int c = 0; c < copies; ++c)
            __builtin_nontemporal_store(res, out + (size_t)c * stride + idx);
    }
}

// ============ MFMA GEMM: C = A[M,K]@B[K,N] (+bias, relu), fp32 via bf16 hi/lo 3-term split ============
template<int NT_IN, int NT_OUT>
__global__ __launch_bounds__(256) void gemm_mfma(const float* __restrict__ A,
                                                 const float* __restrict__ B,
                                                 const float* __restrict__ bias,
                                                 float* __restrict__ C,
                                                 int M, int N, int K, int relu, int rep) {
    __shared__ unsigned Ah[4][64][4], Al[4][64][4], Bh[4][64][4], Bl[4][64][4];  // 16 KiB

    const int nbn = gridDim.x;                       // 4 (gemm1) or 1 (gemm2)
    const int nl  = (nbn == 4) ? 2 : 0;
    const int tot = nbn * gridDim.y;
    int flat = blockIdx.x + nbn * blockIdx.y;
    int q = tot >> 3, r = tot & 7;
    int x8 = flat & 7, i8 = flat >> 3;
    int f2 = (x8 < r ? x8 * (q + 1) : r * (q + 1) + (x8 - r) * q) + i8;
    const int bn = (f2 & (nbn - 1)) * 64;
    const int bm = (f2 >> nl) * 64;

    const int tid  = threadIdx.x;
    const int lane = tid & 63;
    const int wv   = tid >> 6;
    const int wr   = wv >> 1, wc = wv & 1;
    const int lg   = lane >> 4, lr = lane & 15;

    for (int it = 0; it < rep; ++it) {
        asm volatile("" ::: "memory");
        f32x4 acc[2][2] = {};
        for (int k0 = 0; k0 < K; k0 += 32) {
            #pragma unroll
            for (int i = 0; i < 4; ++i) {            // A tile 64x32
                int t  = tid + i * 256;
                int rr = t >> 4, kp = t & 15;
                int gr = bm + rr;
                f32x2 v = {0.f, 0.f};
                if (gr < M) {
                    const f32x2* p = (const f32x2*)(A + (size_t)gr * K + k0 + 2 * kp);
                    v = NT_IN ? __builtin_nontemporal_load(p) : *p;
                }
                unsigned hp, lp;
                split_pair(v.x, v.y, hp, lp);
                Ah[kp >> 2][rr][kp & 3] = hp;
                Al[kp >> 2][rr][kp & 3] = lp;
            }
            #pragma unroll
            for (int i = 0; i < 4; ++i) {            // B tile 32x64
                int t  = tid + i * 256;
                int cc = t & 63, kp = t >> 6;
                const float* p = B + (size_t)(k0 + 2 * kp) * N + bn + cc;
                float v0 = p[0], v1 = p[N];
                unsigned hp, lp;
                split_pair(v0, v1, hp, lp);
                Bh[kp >> 2][cc][kp & 3] = hp;
                Bl[kp >> 2][cc][kp & 3] = lp;
            }
            __syncthreads();

            bf16x8 ah[2], al[2], bh[2], bl[2];
            #pragma unroll
            for (int f = 0; f < 2; ++f) {
                int ar = wr * 32 + f * 16 + lr;
                ah[f] = *(const bf16x8*)&Ah[lg][ar][0];
                al[f] = *(const bf16x8*)&Al[lg][ar][0];
                int bc = wc * 32 + f * 16 + lr;
                bh[f] = *(const bf16x8*)&Bh[lg][bc][0];
                bl[f] = *(const bf16x8*)&Bl[lg][bc][0];
            }
            #pragma unroll
            for (int fi = 0; fi < 2; ++fi)
                #pragma unroll
                for (int fj = 0; fj < 2; ++fj) {
                    acc[fi][fj] = __builtin_amdgcn_mfma_f32_16x16x32_bf16(ah[fi], bh[fj], acc[fi][fj], 0, 0, 0);
                    acc[fi][fj] = __builtin_amdgcn_mfma_f32_16x16x32_bf16(ah[fi], bl[fj], acc[fi][fj], 0, 0, 0);
                    acc[fi][fj] = __builtin_amdgcn_mfma_f32_16x16x32_bf16(al[fi], bh[fj], acc[fi][fj], 0, 0, 0);
                }
            __syncthreads();
        }
        #pragma unroll
        for (int fj = 0; fj < 2; ++fj) {
            int col = bn + wc * 32 + fj * 16 + lr;
            float bv = bias ? bias[col] : 0.f;
            #pragma unroll
            for (int fi = 0; fi < 2; ++fi) {
                #pragma unroll
                for (int rg = 0; rg < 4; ++rg) {
                    int gr = bm + wr * 32 + fi * 16 + lg * 4 + rg;
                    if (gr < M) {
                        float o = acc[fi][fj][rg] + bv;
                        if (relu) o = fmaxf(o, 0.f);
                        if (NT_OUT) __builtin_nontemporal_store(o, C + (size_t)gr * N + col);
                        else        C[(size_t)gr * N + col] = o;
                    }
                }
            }
        }
    }
}

extern "C" void kernel_launch(void* const* d_in, const int* in_sizes, int n_in,
                              void* d_out, int out_size, void* d_ws, size_t ws_size,
                              hipStream_t stream) {
    const float* x  = (const float*)d_in[0];
    const float* W1 = (const float*)d_in[1];
    const float* b1 = (const float*)d_in[2];
    const float* W2 = (const float*)d_in[3];
    const float* b2 = (const float*)d_in[4];
    const int*   ei = (const int*)d_in[5];

    const int n = in_sizes[0] / 128;              // 50000
    const int E = in_sizes[5] / 2;                // 800000
    float* out = (float*)d_out;
    const size_t stride = (size_t)n * 64;
    const int copies = (int)(out_size / stride);  // 24

    // scratch that the fused output kernel READS must live outside d_out
    const size_t needWs = ((size_t)(5 * (size_t)n + 64)            // meta
                           + 2 * ((size_t)E + 8 * (size_t)n)       // edge2
                           + (size_t)n * 64) * sizeof(float);      // H2   (~23.3 MB)
    const bool use_ws = (d_ws != nullptr) && (ws_size >= needWs);

    float* meta  = use_ws ? (float*)d_ws : out;
    float* dinv  = meta;
    int*   cnt   = (int*)(meta + n);
    int*   base  = (int*)(meta + 2 * (size_t)n);
    int*   fill  = (int*)(meta + 3 * (size_t)n);
    int*   total = (int*)(meta + 4 * (size_t)n);
    int2*  edge2 = use_ws ? (int2*)(meta + 5 * (size_t)n + 64)
                          : (int2*)(out + 1 * stride);
    float* H2    = use_ws ? (float*)(edge2 + ((size_t)E + 8 * (size_t)n))
                          : out + 8 * stride;
    float* AGGX  = out + 2 * stride;              // dead before final writes
    float* H1    = out + 4 * stride;
    float* AGG2  = out + 9 * stride;              // fallback only

    // attribution repeats (idempotent); rep=1 restores normal operation
    const int REP_AGG = 8, REP_GEMM = 8, REP_F = 4;

    hipMemsetAsync(cnt, 0, (3 * (size_t)n + 64) * sizeof(int), stream);

    hist_rows    <<<(E + 255) / 256, 256, 0, stream>>>(ei, cnt, E);
    alloc_buckets<<<(n + 255) / 256, 256, 0, stream>>>(cnt, base, fill, dinv, total, edge2, n);
    fill_buckets <<<(E + 255) / 256, 256, 0, stream>>>(ei, ei + E, fill, dinv, edge2, E);

    agg_x<<<(n + 3) / 4, 256, 0, stream>>>(x, base, cnt, edge2, dinv, AGGX, n, REP_AGG);
    gemm_mfma<0, 1><<<dim3(4, (n + 63) / 64), 256, 0, stream>>>(AGGX, W1, b1, H1, n, 256, 128, 1, REP_GEMM);
    gemm_mfma<1, 0><<<dim3(1, (n + 63) / 64), 256, 0, stream>>>(H1, W2, nullptr, H2, n, 64, 256, 0, REP_GEMM);

    if (use_ws) {
        agg_h2_final<<<(n + 3) / 4, 256, 0, stream>>>(H2, base, cnt, edge2, dinv, b2, out, n, copies, REP_F);
    } else {
        agg_h2   <<<(n + 3) / 4, 256, 0, stream>>>(H2, base, cnt, edge2, dinv, b2, AGG2, n, REP_AGG);
        final_out<<<(n + 3) / 4, 256, 0, stream>>>(AGG2, out, n, copies, REP_F);
    }
}

// Round 3
// 606.224 us; speedup vs baseline: 2.8099x; 2.8099x over previous
//
#include <hip/hip_runtime.h>

typedef float  f32x2  __attribute__((ext_vector_type(2)));
typedef float  f32x4  __attribute__((ext_vector_type(4)));
typedef __bf16 bf16x8 __attribute__((ext_vector_type(8)));
typedef unsigned uint4v __attribute__((ext_vector_type(4)));

// split fp32 pair into packed bf16 hi-pair and lo-pair (3-term MFMA emulation)
static __device__ __forceinline__ void split_pair(float a, float b, unsigned& hp, unsigned& lp) {
    __bf16 ha = (__bf16)a, hb = (__bf16)b;
    hp = (unsigned)__builtin_bit_cast(unsigned short, ha) |
         ((unsigned)__builtin_bit_cast(unsigned short, hb) << 16);
    __bf16 la = (__bf16)(a - (float)ha), lb = (__bf16)(b - (float)hb);
    lp = (unsigned)__builtin_bit_cast(unsigned short, la) |
         ((unsigned)__builtin_bit_cast(unsigned short, lb) << 16);
}

// 8 fp32 -> bf16x8 hi + bf16x8 lo (in-register split for gemm2's fp32 A)
static __device__ __forceinline__ void split8(f32x4 u, f32x4 v, bf16x8& h8, bf16x8& l8) {
    float f[8] = {u.x, u.y, u.z, u.w, v.x, v.y, v.z, v.w};
    #pragma unroll
    for (int t = 0; t < 8; ++t) {
        __bf16 h = (__bf16)f[t];
        h8[t] = h;
        l8[t] = (__bf16)(f[t] - (float)h);
    }
}

// ============ CSR bucket build (order-free; buckets padded to multiple of 8) ============
__global__ __launch_bounds__(256) void hist_rows(const int* __restrict__ row, int* __restrict__ cnt, int E) {
    int e = blockIdx.x * 256 + threadIdx.x;
    if (e < E) atomicAdd(&cnt[row[e]], 1);
}

__global__ __launch_bounds__(256) void alloc_buckets(const int* __restrict__ cnt,
                                                     int* __restrict__ base, int* __restrict__ fill,
                                                     float* __restrict__ dinv,
                                                     int* __restrict__ total,
                                                     int2* __restrict__ edge2, int n) {
    int i = blockIdx.x * 256 + threadIdx.x;
    if (i >= n) return;
    int c = cnt[i];
    int cp = (c + 7) & ~7;                 // pad to x8
    int b = atomicAdd(total, cp);
    base[i] = b;
    fill[i] = b;
    dinv[i] = rsqrtf(1.0f + (float)c);     // +1 self-loop
    for (int p = b + c; p < b + cp; ++p) edge2[p] = make_int2(0, 0);  // pad: gathers idx0 * 0.0
}

__global__ __launch_bounds__(256) void fill_buckets(const int* __restrict__ row, const int* __restrict__ col,
                                                    int* __restrict__ fill, const float* __restrict__ dinv,
                                                    int2* __restrict__ edge2, int E) {
    int e = blockIdx.x * 256 + threadIdx.x;
    if (e < E) {
        int r = row[e], c = col[e];
        int pos = atomicAdd(&fill[r], 1);
        edge2[pos] = make_int2(c, __float_as_int(dinv[r] * dinv[c]));
    }
}

// ============ pre-split weights, transposed: W[k][c] -> Wt_hi[c][k], Wt_lo[c][k] (bf16) ============
__global__ __launch_bounds__(256) void split_w(const float* __restrict__ W1, const float* __restrict__ W2,
                                               unsigned short* __restrict__ w1h, unsigned short* __restrict__ w1l,
                                               unsigned short* __restrict__ w2h, unsigned short* __restrict__ w2l) {
    int i = blockIdx.x * 256 + threadIdx.x;
    if (i < 128 * 256) {
        int k = i >> 8, c = i & 255;
        float v = W1[i];
        __bf16 h = (__bf16)v, l = (__bf16)(v - (float)h);
        w1h[(size_t)c * 128 + k] = __builtin_bit_cast(unsigned short, h);
        w1l[(size_t)c * 128 + k] = __builtin_bit_cast(unsigned short, l);
    } else if (i < 128 * 256 + 256 * 64) {
        int j = i - 128 * 256;
        int k = j >> 6, c = j & 63;
        float v = W2[j];
        __bf16 h = (__bf16)v, l = (__bf16)(v - (float)h);
        w2h[(size_t)c * 256 + k] = __builtin_bit_cast(unsigned short, h);
        w2l[(size_t)c * 256 + k] = __builtin_bit_cast(unsigned short, l);
    }
}

// ============ aggregate x (128 feats, float2/lane) -> pre-split bf16 hi/lo planes ============
__global__ __launch_bounds__(256) void agg_x(const float* __restrict__ x,
                                             const int* __restrict__ base, const int* __restrict__ cnt,
                                             const int2* __restrict__ edge2, const float* __restrict__ dinv,
                                             unsigned* __restrict__ AXh, unsigned* __restrict__ AXl, int n) {
    int w = (blockIdx.x * 256 + threadIdx.x) >> 6;
    int lane = threadIdx.x & 63;
    if (w >= n) return;
    float di = dinv[w];
    f32x2 xv = ((const f32x2*)(x + (size_t)w * 128))[lane];
    f32x2 a0 = xv * (di * di);
    f32x2 a1 = {0.f, 0.f}, a2 = {0.f, 0.f}, a3 = {0.f, 0.f};
    const int2* eb = edge2 + base[w];
    int dp = (cnt[w] + 7) & ~7;
    if (dp > 0) {
        int2 e[8];
        #pragma unroll
        for (int u = 0; u < 8; ++u) e[u] = eb[u];
        int j = 0;
        for (; j + 8 < dp; j += 8) {
            f32x2 v[8];
            #pragma unroll
            for (int u = 0; u < 8; ++u)
                v[u] = ((const f32x2*)(x + (size_t)e[u].x * 128))[lane];
            int2 en[8];                        // prefetch next descriptor block under the gathers
            #pragma unroll
            for (int u = 0; u < 8; ++u) en[u] = eb[j + 8 + u];
            #pragma unroll
            for (int u = 0; u < 8; ++u) {
                float nr = __int_as_float(e[u].y);
                f32x2* a = (u & 3) == 0 ? &a0 : (u & 3) == 1 ? &a1 : (u & 3) == 2 ? &a2 : &a3;
                *a += v[u] * nr;
            }
            #pragma unroll
            for (int u = 0; u < 8; ++u) e[u] = en[u];
        }
        {
            f32x2 v[8];
            #pragma unroll
            for (int u = 0; u < 8; ++u)
                v[u] = ((const f32x2*)(x + (size_t)e[u].x * 128))[lane];
            #pragma unroll
            for (int u = 0; u < 8; ++u) {
                float nr = __int_as_float(e[u].y);
                f32x2* a = (u & 3) == 0 ? &a0 : (u & 3) == 1 ? &a1 : (u & 3) == 2 ? &a2 : &a3;
                *a += v[u] * nr;
            }
        }
    }
    f32x2 o = a0 + a1 + a2 + a3;
    unsigned hp, lp;
    split_pair(o.x, o.y, hp, lp);              // identical quantization as before, just relocated
    __builtin_nontemporal_store(hp, AXh + (size_t)w * 64 + lane);
    __builtin_nontemporal_store(lp, AXl + (size_t)w * 64 + lane);
}

// ============ direct-fragment MFMA GEMM: no LDS, no barriers, fragments straight from L1/L2 ============
// Wave computes FI*16 rows x 64 cols. A fragment (row=lr, k=lg*8+j) = 16 contiguous bytes of a
// row-major bf16 plane; B fragment likewise from transposed [col][K] planes.
// APLANES=1: A pre-split (Ah/Al u32 pair-planes [M][K/2]); else fp32 A split in-register.
template<int K_, int FI, int CT, int APLANES, int NTIN, int NTOUT>
__global__ __launch_bounds__(256) void gemm_direct(const unsigned* __restrict__ Ah,
                                                   const unsigned* __restrict__ Al,
                                                   const float* __restrict__ Afp,
                                                   const unsigned short* __restrict__ Bh,
                                                   const unsigned short* __restrict__ Bl,
                                                   const float* __restrict__ bias,
                                                   float* __restrict__ C,
                                                   int M, int N, int relu) {
    int gw = blockIdx.x * 4 + (threadIdx.x >> 6);
    int rt = gw / CT, ct = gw % CT;
    int rows = rt * (FI * 16);
    if (rows >= M) return;
    int lane = threadIdx.x & 63, lg = lane >> 4, lr = lane & 15;

    size_t boff[4];
    #pragma unroll
    for (int j = 0; j < 4; ++j)
        boff[j] = (size_t)(ct * 64 + j * 16 + lr) * K_ + lg * 8;     // u16 units

    size_t aoff[FI];
    #pragma unroll
    for (int i = 0; i < FI; ++i) {
        int ar = rows + i * 16 + lr;
        if (ar >= M) ar = M - 1;                                      // clamp; rows>=M discarded at store
        aoff[i] = APLANES ? (size_t)ar * (K_ / 2) + lg * 4            // u32 units
                          : (size_t)ar * K_ + lg * 8;                 // f32 units
    }

    f32x4 acc[FI][4] = {};

    #pragma unroll 2
    for (int k0 = 0; k0 < K_; k0 += 32) {
        bf16x8 a_h[FI], a_l[FI];
        #pragma unroll
        for (int i = 0; i < FI; ++i) {
            if (APLANES) {
                a_h[i] = __builtin_bit_cast(bf16x8, *(const uint4v*)(Ah + aoff[i] + (k0 >> 1)));
                a_l[i] = __builtin_bit_cast(bf16x8, *(const uint4v*)(Al + aoff[i] + (k0 >> 1)));
            } else {
                const f32x4* p = (const f32x4*)(Afp + aoff[i] + k0);
                f32x4 u = NTIN ? __builtin_nontemporal_load(p)     : p[0];
                f32x4 v = NTIN ? __builtin_nontemporal_load(p + 1) : p[1];
                split8(u, v, a_h[i], a_l[i]);
            }
        }
        #pragma unroll
        for (int j = 0; j < 4; ++j) {
            bf16x8 b_h = __builtin_bit_cast(bf16x8, *(const uint4v*)(Bh + boff[j] + k0));
            bf16x8 b_l = __builtin_bit_cast(bf16x8, *(const uint4v*)(Bl + boff[j] + k0));
            #pragma unroll
            for (int i = 0; i < FI; ++i) {
                acc[i][j] = __builtin_amdgcn_mfma_f32_16x16x32_bf16(a_h[i], b_h, acc[i][j], 0, 0, 0);
                acc[i][j] = __builtin_amdgcn_mfma_f32_16x16x32_bf16(a_h[i], b_l, acc[i][j], 0, 0, 0);
                acc[i][j] = __builtin_amdgcn_mfma_f32_16x16x32_bf16(a_l[i], b_h, acc[i][j], 0, 0, 0);
            }
        }
    }

    #pragma unroll
    for (int j = 0; j < 4; ++j) {
        int col = ct * 64 + j * 16 + lr;
        float bv = bias ? bias[col] : 0.f;
        #pragma unroll
        for (int i = 0; i < FI; ++i)
            #pragma unroll
            for (int rg = 0; rg < 4; ++rg) {
                int gr = rows + i * 16 + lg * 4 + rg;
                if (gr < M) {
                    float o = acc[i][j][rg] + bv;
                    if (relu) o = fmaxf(o, 0.f);
                    if (NTOUT) __builtin_nontemporal_store(o, C + (size_t)gr * N + col);
                    else       C[(size_t)gr * N + col] = o;
                }
            }
    }
}

// ============ fused: aggregate H2 (64 feats) + bias + log_softmax + 24-copy broadcast ============
__global__ __launch_bounds__(256) void agg_h2_final(const float* __restrict__ H2,
                                                    const int* __restrict__ base, const int* __restrict__ cnt,
                                                    const int2* __restrict__ edge2, const float* __restrict__ dinv,
                                                    const float* __restrict__ b2,
                                                    float* __restrict__ out, int n, int copies) {
    int w = (blockIdx.x * 256 + threadIdx.x) >> 6;
    int lane = threadIdx.x & 63;
    if (w >= n) return;
    float di = dinv[w];
    float a0 = H2[(size_t)w * 64 + lane] * di * di;
    float a1 = 0.f, a2 = 0.f, a3 = 0.f;
    const int2* eb = edge2 + base[w];
    int dp = (cnt[w] + 7) & ~7;
    if (dp > 0) {
        int2 e[8];
        #pragma unroll
        for (int u = 0; u < 8; ++u) e[u] = eb[u];
        int j = 0;
        for (; j + 8 < dp; j += 8) {
            float v[8];
            #pragma unroll
            for (int u = 0; u < 8; ++u) v[u] = H2[(size_t)e[u].x * 64 + lane];
            int2 en[8];
            #pragma unroll
            for (int u = 0; u < 8; ++u) en[u] = eb[j + 8 + u];
            #pragma unroll
            for (int u = 0; u < 8; ++u) {
                float nr = __int_as_float(e[u].y);
                float* a = (u & 3) == 0 ? &a0 : (u & 3) == 1 ? &a1 : (u & 3) == 2 ? &a2 : &a3;
                *a = fmaf(v[u], nr, *a);
            }
            #pragma unroll
            for (int u = 0; u < 8; ++u) e[u] = en[u];
        }
        {
            float v[8];
            #pragma unroll
            for (int u = 0; u < 8; ++u) v[u] = H2[(size_t)e[u].x * 64 + lane];
            #pragma unroll
            for (int u = 0; u < 8; ++u) {
                float nr = __int_as_float(e[u].y);
                float* a = (u & 3) == 0 ? &a0 : (u & 3) == 1 ? &a1 : (u & 3) == 2 ? &a2 : &a3;
                *a = fmaf(v[u], nr, *a);
            }
        }
    }
    float v = a0 + a1 + a2 + a3 + b2[lane];
    float m = v;
    #pragma unroll
    for (int off = 32; off > 0; off >>= 1) m = fmaxf(m, __shfl_xor(m, off, 64));
    float e = expf(v - m);
    float s = e;
    #pragma unroll
    for (int off = 32; off > 0; off >>= 1) s += __shfl_xor(s, off, 64);
    float res = v - m - logf(s);
    size_t idx = (size_t)w * 64 + lane;
    size_t stride = (size_t)n * 64;
    for (int c = 0; c < copies; ++c)
        __builtin_nontemporal_store(res, out + (size_t)c * stride + idx);
}

// ============ fallback unfused pair (d_out-as-workspace layout) ============
__global__ __launch_bounds__(256) void agg_h2(const float* __restrict__ H2,
                                              const int* __restrict__ base, const int* __restrict__ cnt,
                                              const int2* __restrict__ edge2, const float* __restrict__ dinv,
                                              const float* __restrict__ b2,
                                              float* __restrict__ AGG2, int n) {
    int w = (blockIdx.x * 256 + threadIdx.x) >> 6;
    int lane = threadIdx.x & 63;
    if (w >= n) return;
    float di = dinv[w];
    float a0 = H2[(size_t)w * 64 + lane] * di * di;
    float a1 = 0.f, a2 = 0.f, a3 = 0.f;
    const int2* eb = edge2 + base[w];
    int dp = (cnt[w] + 7) & ~7;
    for (int j = 0; j < dp; j += 8) {
        int2 e[8];
        #pragma unroll
        for (int u = 0; u < 8; ++u) e[u] = eb[j + u];
        float v[8];
        #pragma unroll
        for (int u = 0; u < 8; ++u) v[u] = H2[(size_t)e[u].x * 64 + lane];
        #pragma unroll
        for (int u = 0; u < 8; ++u) {
            float nr = __int_as_float(e[u].y);
            float* a = (u & 3) == 0 ? &a0 : (u & 3) == 1 ? &a1 : (u & 3) == 2 ? &a2 : &a3;
            *a = fmaf(v[u], nr, *a);
        }
    }
    __builtin_nontemporal_store(a0 + a1 + a2 + a3 + b2[lane], AGG2 + (size_t)w * 64 + lane);
}

__global__ __launch_bounds__(256) void final_out(const float* __restrict__ AGG2,
                                                 float* __restrict__ out, int n, int copies) {
    int w = (blockIdx.x * 256 + threadIdx.x) >> 6;
    int lane = threadIdx.x & 63;
    if (w >= n) return;
    size_t idx = (size_t)w * 64 + lane;
    float v = __builtin_nontemporal_load(AGG2 + idx);
    float m = v;
    #pragma unroll
    for (int off = 32; off > 0; off >>= 1) m = fmaxf(m, __shfl_xor(m, off, 64));
    float e = expf(v - m);
    float s = e;
    #pragma unroll
    for (int off = 32; off > 0; off >>= 1) s += __shfl_xor(s, off, 64);
    float res = v - m - logf(s);
    size_t stride = (size_t)n * 64;
    for (int c = 0; c < copies; ++c)
        __builtin_nontemporal_store(res, out + (size_t)c * stride + idx);
}

extern "C" void kernel_launch(void* const* d_in, const int* in_sizes, int n_in,
                              void* d_out, int out_size, void* d_ws, size_t ws_size,
                              hipStream_t stream) {
    const float* x  = (const float*)d_in[0];
    const float* W1 = (const float*)d_in[1];
    const float* b1 = (const float*)d_in[2];
    const float* W2 = (const float*)d_in[3];
    const float* b2 = (const float*)d_in[4];
    const int*   ei = (const int*)d_in[5];

    const int n = in_sizes[0] / 128;              // 50000
    const int E = in_sizes[5] / 2;                // 800000
    float* out = (float*)d_out;
    const size_t stride = (size_t)n * 64;
    const int copies = (int)(out_size / stride);  // 24

    // ws requirement: meta + edge2 + H2 + W split planes (all read by pre-final stages)
    const size_t metaF  = 5 * (size_t)n + 64;
    const size_t edge2F = 2 * ((size_t)E + 8 * (size_t)n);
    const size_t h2F    = (size_t)n * 64;
    const size_t wF     = 32768 + 16384;          // u16 counts halved to floats: (2*32768 + 2*16384)/2
    const size_t needWs = (metaF + edge2F + h2F + wF) * sizeof(float);
    const bool use_ws = (d_ws != nullptr) && (ws_size >= needWs);

    float* meta  = use_ws ? (float*)d_ws : out;
    float* dinv  = meta;
    int*   cnt   = (int*)(meta + n);
    int*   base  = (int*)(meta + 2 * (size_t)n);
    int*   fill  = (int*)(meta + 3 * (size_t)n);
    int*   total = (int*)(meta + 4 * (size_t)n);
    int2*  edge2 = use_ws ? (int2*)(meta + metaF) : (int2*)(out + 1 * stride);
    float* H2    = use_ws ? (float*)(edge2 + (edge2F / 2)) : out + 8 * stride;
    unsigned short* w1h = use_ws ? (unsigned short*)(H2 + h2F)
                                 : (unsigned short*)(out + 10 * stride);
    unsigned short* w1l = w1h + 32768;
    unsigned short* w2h = w1l + 32768;
    unsigned short* w2l = w2h + 16384;

    unsigned* AXh = (unsigned*)(out + 2 * stride);  // pre-split AGGX planes (dead before final)
    unsigned* AXl = (unsigned*)(out + 3 * stride);
    float*    H1  = out + 4 * stride;               // regions 4-7 (51.2 MB)
    float*    AGG2 = out + 9 * stride;              // fallback only

    hipMemsetAsync(cnt, 0, (3 * (size_t)n + 64) * sizeof(int), stream);

    split_w<<<(128 * 256 + 256 * 64 + 255) / 256, 256, 0, stream>>>(W1, W2, w1h, w1l, w2h, w2l);

    hist_rows    <<<(E + 255) / 256, 256, 0, stream>>>(ei, cnt, E);
    alloc_buckets<<<(n + 255) / 256, 256, 0, stream>>>(cnt, base, fill, dinv, total, edge2, n);
    fill_buckets <<<(E + 255) / 256, 256, 0, stream>>>(ei, ei + E, fill, dinv, edge2, E);

    // layer 1: aggregate (emits split planes) -> direct-fragment MFMA GEMM
    agg_x<<<(n + 3) / 4, 256, 0, stream>>>(x, base, cnt, edge2, dinv, AXh, AXl, n);
    {   // M=n, N=256, K=128; waves = ceil(n/32)*4; 4 waves/block
        int rtc = (n + 31) / 32;
        gemm_direct<128, 2, 4, 1, 0, 1><<<rtc, 256, 0, stream>>>(
            AXh, AXl, nullptr, w1h, w1l, b1, H1, n, 256, 1);
    }
    // layer 2: M=n, N=64, K=256; fp32 A (H1) split in-register, NT read
    {
        int rtc = (n + 15) / 16;                  // FI=1 -> 16-row waves for TLP
        gemm_direct<256, 1, 1, 0, 1, 0><<<(rtc + 3) / 4, 256, 0, stream>>>(
            nullptr, nullptr, H1, w2h, w2l, nullptr, H2, n, 64, 0);
    }

    if (use_ws) {
        agg_h2_final<<<(n + 3) / 4, 256, 0, stream>>>(H2, base, cnt, edge2, dinv, b2, out, n, copies);
    } else {
        agg_h2   <<<(n + 3) / 4, 256, 0, stream>>>(H2, base, cnt, edge2, dinv, b2, AGG2, n);
        final_out<<<(n + 3) / 4, 256, 0, stream>>>(AGG2, out, n, copies);
    }
}